// Round 1
// 264.475 us; speedup vs baseline: 1.0802x; 1.0802x over previous
//
#include <hip/hip_runtime.h>

#define NQ 1764
#define NQP 1792             // keys padded to 28*64, zero-filled by prep
#define DIM 256
#define KT 32                // keys per attn tile
#define NT_G 28              // tiles per key-group (2 groups x 28 = 56 total)
#define QBLK 112             // queries stored per block (16 blocks/batch)

// ---- attn LDS map (halfword units) ----
// two key-groups, each double-buffered: 4 x BUF_SZ, then 8-wave P region
#define RM_SZ (KT * DIM)                  // 8192 hw: [32 keys][256 d]
#define TR_SZ (DIM * KT)                  // 8192 hw: [256 d][32 keys]
#define BUF_SZ (RM_SZ + TR_SZ)            // 16384
#define P_OFF (4 * BUF_SZ)                // 65536
#define P_STRIDE 40
#define SM_TOTAL (P_OFF + 8 * 32 * P_STRIDE)   // 75776 hw = 151552 B

// ---- epilogue merge map (float units, reuses sm; all tile/P data dead) ----
#define PAIR_F 8320          // per wave-pair: [32 q][260] fp32 (260 = pad vs conflicts)
#define L_OFF_F (4 * PAIR_F) // 33280 .. 33407: group-1 row sums l

// ---- workspace map (ushort units) ----
#define WS_MRM_SZ (16 * NQP * DIM)
#define WS_MTR_SZ (16 * DIM * NQP)

typedef __attribute__((ext_vector_type(4))) short short4v;
typedef __attribute__((ext_vector_type(8))) short short8v;
typedef __attribute__((ext_vector_type(4))) float float4v;

static __device__ __forceinline__ ushort f2bf(float f) {
  union { float f; unsigned u; } v; v.f = f;
  return (ushort)((v.u + 0x7FFFu + ((v.u >> 16) & 1u)) >> 16);  // RNE
}

// async global->LDS DMA, 16 B per lane; LDS dest = wave-uniform base + lane*16
static __device__ __forceinline__ void dma16(const void* g, void* l) {
  __builtin_amdgcn_global_load_lds(
      (__attribute__((address_space(1))) void*)(void*)g,
      (__attribute__((address_space(3))) void*)l, 16, 0, 0);
}

// ============================ prep: m -> bf16 RM + TR ============================
__global__ __launch_bounds__(256)
void prep_m(const float* __restrict__ mg, ushort* __restrict__ mrm,
            ushort* __restrict__ mtr)
{
  __shared__ float smf[64 * 260];
  const int tid = threadIdx.x;
  const int b   = blockIdx.x & 15;
  const int kt  = blockIdx.x >> 4;      // 0..27, 64-key chunks
  const int k0  = kt * 64;
  const float* mb = mg + (size_t)b * NQ * DIM;

  #pragma unroll
  for (int i = 0; i < 16; ++i) {
    const int idx = i * 256 + tid;
    const int row = idx >> 6;
    const int c4  = (idx & 63) * 4;
    const int gk  = k0 + row;
    float4v v = (gk < NQ) ? *(const float4v*)(mb + (size_t)gk * DIM + c4)
                          : (float4v){0.f, 0.f, 0.f, 0.f};
    *(float4v*)&smf[row * 260 + c4] = v;
    union { short4v v4; short e[4]; } h;
    #pragma unroll
    for (int j = 0; j < 4; ++j) h.e[j] = (short)f2bf(v[j]);
    *(short4v*)(mrm + ((size_t)b * NQP + k0 + row) * DIM + c4) = h.v4;
  }
  __syncthreads();

  const int d = tid;
  ushort* dst = mtr + ((size_t)b * DIM + d) * NQP + k0;
  #pragma unroll
  for (int kc = 0; kc < 8; ++kc) {
    union { short8v v; short e[8]; } u;
    #pragma unroll
    for (int j = 0; j < 8; ++j)
      u.e[j] = (short)f2bf(smf[(kc * 8 + j) * 260 + d]);
    *(short8v*)(dst + kc * 8) = u.v;
  }
}

// ============================ attention ============================
// Block = 8 waves = 512 threads, 1 block/CU -> 2 waves/SIMD (was 1: latency-
// bound at Occupancy 11.5%). Wave pair (wg, wg+4) owns the same 32 queries;
// group g = w>>2 streams key tiles g, g+2, g+4, ... (28 tiles each) with its
// own double-buffered LDS pair. No max-subtraction (|s| small, w_lin cancels
// in softmax), so the merge is exact: O = O_a + O_b, l = l_a + l_b, exchanged
// through LDS in the epilogue.

static __device__ __forceinline__ void stage_tile(const ushort* mrb, const ushort* mtb,
                                                  ushort* smb, int k0, int wg, int lane)
{
  // RM [k][cs] <- global d-chunk cs^(k&7)  (swizzle in the global address)
  #pragma unroll
  for (int j = 0; j < 4; ++j) {
    const int L  = (wg * 4 + j) * 64 + lane;   // 0..1023
    const int k  = L >> 5;
    const int cs = L & 31;
    const int gc = cs ^ (k & 7);
    dma16(mrb + (size_t)(k0 + k) * DIM + gc * 8, smb + (wg * 4 + j) * 512);
  }
  // TR [d][t] <- global key-chunk t^(d&3)
  #pragma unroll
  for (int j = 0; j < 4; ++j) {
    const int L = (wg * 4 + j) * 64 + lane;
    const int d = L >> 2;
    const int t = L & 3;
    const int kc = t ^ (d & 3);
    dma16(mtb + (size_t)d * NQP + k0 + kc * 8, smb + RM_SZ + (wg * 4 + j) * 512);
  }
}

__global__ __launch_bounds__(512, 2)
void attn_fused(const float* __restrict__ x, const ushort* __restrict__ mrm,
                const ushort* __restrict__ mtr, const int* __restrict__ maskg,
                const float* __restrict__ scale, float* __restrict__ out)
{
  __shared__ ushort sm[SM_TOTAL];
  const int tid  = threadIdx.x;
  const int w    = tid >> 6;      // 0..7
  const int lane = tid & 63;
  const int l15  = lane & 15;
  const int quad = lane >> 4;
  const int l7   = l15 & 7;
  const int g    = w >> 2;        // key group: 0 = even tiles, 1 = odd tiles
  const int wg   = w & 3;         // wave-within-group = query sub-block

  const int b      = blockIdx.x & 15;
  const int qblk   = blockIdx.x >> 4;     // 0..15
  const int qbase0 = qblk * QBLK;
  const int qbase  = qbase0 + wg * 32;

  const float*  xb  = x + (size_t)b * NQ * DIM;
  const ushort* mrb = mrm + (size_t)b * NQP * DIM;
  const ushort* mtb = mtr + (size_t)b * DIM * NQP;
  const int*    mkb = maskg + (size_t)b * NQ;
  float*        ob  = out + (size_t)b * NQ * (2 * DIM);

  // ---- resident Q fragments: two 16-q subtiles, Q = x*scale, bf16, A-layout ----
  short8v qa0[8], qa1[8];
  {
    int q0 = qbase + l15;      q0 = q0 < NQ ? q0 : NQ - 1;
    int q1 = qbase + 16 + l15; q1 = q1 < NQ ? q1 : NQ - 1;
    const float* xr0 = xb + (size_t)q0 * DIM;
    const float* xr1 = xb + (size_t)q1 * DIM;
    #pragma unroll
    for (int kk = 0; kk < 8; ++kk) {
      const int dof = kk * 32 + quad * 8;
      const float4v sa = *(const float4v*)(scale + dof);
      const float4v sb = *(const float4v*)(scale + dof + 4);
      const float4v a0 = *(const float4v*)(xr0 + dof);
      const float4v a1 = *(const float4v*)(xr0 + dof + 4);
      const float4v b0 = *(const float4v*)(xr1 + dof);
      const float4v b1 = *(const float4v*)(xr1 + dof + 4);
      union { short8v v; short e[8]; } u0, u1;
      #pragma unroll
      for (int j = 0; j < 4; ++j) {
        u0.e[j]     = (short)f2bf(a0[j] * sa[j]);
        u0.e[j + 4] = (short)f2bf(a1[j] * sb[j]);
        u1.e[j]     = (short)f2bf(b0[j] * sa[j]);
        u1.e[j + 4] = (short)f2bf(b1[j] * sb[j]);
      }
      qa0[kk] = u0.v;
      qa1[kk] = u1.v;
    }
  }

  float4v o0[16], o1[16];
  #pragma unroll
  for (int dt = 0; dt < 16; ++dt) {
    o0[dt] = (float4v){0.f, 0.f, 0.f, 0.f};
    o1[dt] = (float4v){0.f, 0.f, 0.f, 0.f};
  }
  float l0[4] = {0.f, 0.f, 0.f, 0.f};
  float l1[4] = {0.f, 0.f, 0.f, 0.f};

  // prefetch this group's tile 0 (tile index g) -> group buf 0
  stage_tile(mrb, mtb, sm + g * 2 * BUF_SZ, g * KT, wg, lane);

  #pragma unroll 1
  for (int t = 0; t < NT_G; ++t) {
    __syncthreads();   // drains this wave's DMA (vmcnt 0) + syncs buffer reuse
    if (t + 1 < NT_G)
      stage_tile(mrb, mtb, sm + (g * 2 + ((t + 1) & 1)) * BUF_SZ,
                 (g + 2 * (t + 1)) * KT, wg, lane);

    const int k0 = (g + 2 * t) * KT;
    const ushort* rmp = sm + (g * 2 + (t & 1)) * BUF_SZ;
    const ushort* trp = rmp + RM_SZ;

    bool mv[2];
    #pragma unroll
    for (int ks = 0; ks < 2; ++ks) {
      const int key = k0 + ks * 16 + l15;
      mv[ks] = (key < NQ) && (mkb[key < NQ ? key : 0] != 0);
    }

    // ---- S = Q·m^T (B-frag shared by both q-subtiles), p = mask?exp(s):0 ----
    #pragma unroll
    for (int ks = 0; ks < 2; ++ks) {
      float4v s0 = (float4v){0.f, 0.f, 0.f, 0.f};
      float4v s1 = (float4v){0.f, 0.f, 0.f, 0.f};
      const ushort* rowp = rmp + (ks * 16 + l15) * DIM;
      #pragma unroll
      for (int kk = 0; kk < 8; ++kk) {
        const short8v bv = *(const short8v*)(rowp + (((kk * 4 + quad) ^ l7) * 8));
        s0 = __builtin_amdgcn_mfma_f32_16x16x32_bf16(qa0[kk], bv, s0, 0, 0, 0);
        s1 = __builtin_amdgcn_mfma_f32_16x16x32_bf16(qa1[kk], bv, s1, 0, 0, 0);
      }
      #pragma unroll
      for (int r = 0; r < 4; ++r) {
        const float p0 = mv[ks] ? exp2f(s0[r] * 1.44269504089f) : 0.0f;
        const float p1 = mv[ks] ? exp2f(s1[r] * 1.44269504089f) : 0.0f;
        l0[r] += p0;
        l1[r] += p1;
        sm[P_OFF + (w * 32 + quad * 4 + r) * P_STRIDE + ks * 16 + l15] = f2bf(p0);
        sm[P_OFF + (w * 32 + 16 + quad * 4 + r) * P_STRIDE + ks * 16 + l15] = f2bf(p1);
      }
    }

    // ---- O += P·m (B-frag shared by both q-subtiles) ----
    {
      const short8v pa0 = *(const short8v*)&sm[P_OFF + (w * 32 + l15) * P_STRIDE + quad * 8];
      const short8v pa1 = *(const short8v*)&sm[P_OFF + (w * 32 + 16 + l15) * P_STRIDE + quad * 8];
      #pragma unroll
      for (int dt = 0; dt < 16; ++dt) {
        const int d = dt * 16 + l15;
        const short8v bv = *(const short8v*)(trp + d * KT + ((quad ^ (d & 3)) * 8));
        o0[dt] = __builtin_amdgcn_mfma_f32_16x16x32_bf16(pa0, bv, o0[dt], 0, 0, 0);
        o1[dt] = __builtin_amdgcn_mfma_f32_16x16x32_bf16(pa1, bv, o1[dt], 0, 0, 0);
      }
    }
  }

  // ---- reduce l over the 16 lanes of each quad (raw sums; inverse after merge) ----
  float la0[4], la1[4];
  #pragma unroll
  for (int r = 0; r < 4; ++r) {
    float a = l0[r], c = l1[r];
    a += __shfl_xor(a, 1); a += __shfl_xor(a, 2);
    a += __shfl_xor(a, 4); a += __shfl_xor(a, 8);
    c += __shfl_xor(c, 1); c += __shfl_xor(c, 2);
    c += __shfl_xor(c, 4); c += __shfl_xor(c, 8);
    la0[r] = a;
    la1[r] = c;
  }

  __syncthreads();   // tiles + P dead; reuse LDS for the group merge
  float* fsm = (float*)sm;

  // ---- group 1 publishes its partial O and l ----
  if (g == 1) {
    float* pr = fsm + wg * PAIR_F;
    #pragma unroll
    for (int dt = 0; dt < 16; ++dt)
      #pragma unroll
      for (int r = 0; r < 4; ++r) {
        pr[(quad * 4 + r) * 260 + dt * 16 + l15]      = o0[dt][r];
        pr[(16 + quad * 4 + r) * 260 + dt * 16 + l15] = o1[dt][r];
      }
    if (l15 == 0) {
      #pragma unroll
      for (int r = 0; r < 4; ++r) {
        fsm[L_OFF_F + wg * 32 + quad * 4 + r]      = la0[r];
        fsm[L_OFF_F + wg * 32 + 16 + quad * 4 + r] = la1[r];
      }
    }
  }
  __syncthreads();

  // ---- group 0 merges: O += O_b, l += l_b, then inverse ----
  float il0[4], il1[4];
  if (g == 0) {
    float* pr = fsm + wg * PAIR_F;
    #pragma unroll
    for (int dt = 0; dt < 16; ++dt)
      #pragma unroll
      for (int r = 0; r < 4; ++r) {
        o0[dt][r] += pr[(quad * 4 + r) * 260 + dt * 16 + l15];
        o1[dt][r] += pr[(16 + quad * 4 + r) * 260 + dt * 16 + l15];
      }
    #pragma unroll
    for (int r = 0; r < 4; ++r) {
      il0[r] = 1.0f / (la0[r] + fsm[L_OFF_F + wg * 32 + quad * 4 + r]);
      il1[r] = 1.0f / (la1[r] + fsm[L_OFF_F + wg * 32 + 16 + quad * 4 + r]);
    }
  }
  __syncthreads();   // merge region dead; waves 0-3 reuse it for O transpose

  if (g == 0) {
    // ---- O transpose through LDS + coalesced float4 stores ----
    float* ew = fsm + wg * 4160;   // per-wave [16 q][260] fp32
    #pragma unroll
    for (int qs = 0; qs < 2; ++qs) {
      #pragma unroll
      for (int dt = 0; dt < 16; ++dt)
        #pragma unroll
        for (int r = 0; r < 4; ++r)
          ew[(quad * 4 + r) * 260 + dt * 16 + l15] =
              qs ? (o1[dt][r] * il1[r]) : (o0[dt][r] * il0[r]);
      #pragma unroll
      for (int i = 0; i < 4; ++i)
        #pragma unroll
        for (int jj = 0; jj < 4; ++jj) {
          const int row = i * 4 + quad;
          const int lq  = wg * 32 + qs * 16 + row;
          const int q   = qbase0 + lq;
          if (lq < QBLK && q < NQ) {
            const float4v v = *(const float4v*)&ew[row * 260 + (jj * 16 + l15) * 4];
            *(float4v*)(ob + (size_t)q * (2 * DIM) + DIM + (jj * 16 + l15) * 4) = v;
          }
        }
    }
  } else {
    // ---- copy x into first half of concat (block's own 112 queries) ----
    const int tid2 = tid - 256;
    #pragma unroll
    for (int i = 0; i < 28; ++i) {
      const int idx = i * 256 + tid2;     // 0..7167
      const int row = idx >> 6;           // 0..111
      const int c4  = (idx & 63) * 4;
      const int q   = qbase0 + row;
      if (q < NQ) {
        const float4v v = *(const float4v*)(xb + (size_t)q * DIM + c4);
        *(float4v*)(ob + (size_t)q * (2 * DIM) + c4) = v;
      }
    }
  }
}

extern "C" void kernel_launch(void* const* d_in, const int* in_sizes, int n_in,
                              void* d_out, int out_size, void* d_ws, size_t ws_size,
                              hipStream_t stream) {
  const float* x     = (const float*)d_in[0];
  const float* mem   = (const float*)d_in[1];
  const int*   mask  = (const int*)d_in[2];
  // d_in[3] = w_lin: cancels in softmax (per-row constant) — unused
  const float* scale = (const float*)d_in[4];
  float* out = (float*)d_out;

  ushort* wsm = (ushort*)d_ws;               // bf16 m, row-major [16][1792][256]
  ushort* wst = wsm + WS_MRM_SZ;             // bf16 m, transposed [16][256][1792]

  prep_m<<<dim3(448), dim3(256), 0, stream>>>(mem, wsm, wst);
  // 16 batches x 16 q-blocks of 112 queries = 256 blocks = 1 per CU,
  // 8 waves/block (2 key-groups x 4 query-waves) = 2 waves/SIMD
  attn_fused<<<dim3(256), dim3(512), 0, stream>>>(x, wsm, wst, mask, scale, out);
}